// Round 10
// baseline (1610.202 us; speedup 1.0000x reference)
//
#include <hip/hip_runtime.h>
#include <cstdint>

#define SLOPE 0.33f

static constexpr int B_   = 64;
static constexpr int E1_  = 8978;
static constexpr int E2_  = 4489;
static constexpr int N1_  = B_ * E1_;      // 574592
static constexpr int N2_  = B_ * E2_;      // 287296
static constexpr int DEG_ = 16;
static constexpr int QTR_ = 2245;          // ceil(E1_/4)
static constexpr int QTR2_ = 1123;         // ceil(E2_/4)
static constexpr int MVGRID = (N2_ * 32) / 256;   // 35912 (exact)
static constexpr double EPS_ = 1e-5;

__device__ __forceinline__ float lrelu(float v) { return v > 0.f ? v : SLOPE * v; }

// =====================================================================
// Layer 0: 1 channel. Per-graph x slab staged in LDS; edges of node g are
// [g*16, g*16+16) by construction (dst sorted). grid = 64 graphs * 4 quarters.
// =====================================================================
__global__ __launch_bounds__(256) void k0_mv1(const float* __restrict__ x,
    const int* __restrict__ src, const float* __restrict__ ew, float* __restrict__ T1) {
  __shared__ float sx[E1_];
  int g = blockIdx.x >> 2, q = blockIdx.x & 3;
  int gbase = g * E1_;
  for (int j = threadIdx.x; j < E1_; j += 256) sx[j] = x[gbase + j];
  __syncthreads();
  int start = q * QTR_, end = min(start + QTR_, E1_);
  for (int i = start + (int)threadIdx.x; i < end; i += 256) {
    int node = gbase + i;
    const int4* s4 = (const int4*)(src + (size_t)node * DEG_);
    const float4* w4 = (const float4*)(ew + (size_t)node * DEG_);
    float acc = 0.f;
#pragma unroll
    for (int j = 0; j < 4; ++j) {
      int4 s = s4[j]; float4 w = w4[j];
      acc += w.x * sx[s.x - gbase] + w.y * sx[s.y - gbase]
           + w.z * sx[s.z - gbase] + w.w * sx[s.w - gbase];
    }
    T1[node] = sx[i] - acc;   // T1 = x - L x
  }
}

__global__ __launch_bounds__(256) void k0_mv2(const float* __restrict__ x,
    const int* __restrict__ src, const float* __restrict__ ew,
    const float* __restrict__ T1, float* __restrict__ T2) {
  __shared__ float sT[E1_];
  int g = blockIdx.x >> 2, q = blockIdx.x & 3;
  int gbase = g * E1_;
  for (int j = threadIdx.x; j < E1_; j += 256) sT[j] = T1[gbase + j];
  __syncthreads();
  int start = q * QTR_, end = min(start + QTR_, E1_);
  for (int i = start + (int)threadIdx.x; i < end; i += 256) {
    int node = gbase + i;
    const int4* s4 = (const int4*)(src + (size_t)node * DEG_);
    const float4* w4 = (const float4*)(ew + (size_t)node * DEG_);
    float acc = 0.f;
#pragma unroll
    for (int j = 0; j < 4; ++j) {
      int4 s = s4[j]; float4 w = w4[j];
      acc += w.x * sT[s.x - gbase] + w.y * sT[s.y - gbase]
           + w.z * sT[s.z - gbase] + w.w * sT[s.w - gbase];
    }
    T2[node] = (3.f * sT[i] - acc - x[node]) * 0.5f;  // T2 = (3T1 - L T1 - T0)/2
  }
}

// T3 = (5T2 - L T2 - 2T1)/3, plus moment accumulation for layer-0 BN.
__global__ __launch_bounds__(256) void k0_mv3(const float* __restrict__ x,
    const int* __restrict__ src, const float* __restrict__ ew,
    const float* __restrict__ T1, const float* __restrict__ T2,
    float* __restrict__ T3, double* mom) {
  __shared__ float sT[E1_];
  __shared__ double sred[4 * 14];
  int g = blockIdx.x >> 2, q = blockIdx.x & 3;
  int gbase = g * E1_;
  for (int j = threadIdx.x; j < E1_; j += 256) sT[j] = T2[gbase + j];
  __syncthreads();
  double m[14];
#pragma unroll
  for (int j = 0; j < 14; ++j) m[j] = 0.0;
  int start = q * QTR_, end = min(start + QTR_, E1_);
  for (int i = start + (int)threadIdx.x; i < end; i += 256) {
    int node = gbase + i;
    const int4* s4 = (const int4*)(src + (size_t)node * DEG_);
    const float4* w4 = (const float4*)(ew + (size_t)node * DEG_);
    float acc = 0.f;
#pragma unroll
    for (int j = 0; j < 4; ++j) {
      int4 s = s4[j]; float4 w = w4[j];
      acc += w.x * sT[s.x - gbase] + w.y * sT[s.y - gbase]
           + w.z * sT[s.z - gbase] + w.w * sT[s.w - gbase];
    }
    float t1 = T1[node];
    float t2 = sT[i];
    float t3 = (5.f * t2 - acc - 2.f * t1) * (1.f / 3.f);
    T3[node] = t3;
    double d0 = x[node], d1 = t1, d2 = t2, d3 = t3;
    m[0] += d0; m[1] += d1; m[2] += d2; m[3] += d3;
    m[4] += d0 * d0; m[5] += d0 * d1; m[6] += d0 * d2; m[7] += d0 * d3;
    m[8] += d1 * d1; m[9] += d1 * d2; m[10] += d1 * d3;
    m[11] += d2 * d2; m[12] += d2 * d3; m[13] += d3 * d3;
  }
  int lane = threadIdx.x & 63, wid = threadIdx.x >> 6;
#pragma unroll
  for (int j = 0; j < 14; ++j) {
    double v = m[j];
    for (int o = 32; o; o >>= 1) v += __shfl_down(v, o);
    if (lane == 0) sred[wid * 14 + j] = v;
  }
  __syncthreads();
  if (threadIdx.x < 14) {
    double s = sred[threadIdx.x] + sred[14 + threadIdx.x] + sred[28 + threadIdx.x] + sred[42 + threadIdx.x];
    atomicAdd(&mom[threadIdx.x], s);
  }
}

// BN params for layer 0 (b0 cancels in BN exactly).
__global__ void k0_params(const double* __restrict__ mom, const float* __restrict__ W0,
    const float* __restrict__ g0, const float* __restrict__ be0,
    float* __restrict__ scale0, float* __restrict__ shiftE0) {
  int c = threadIdx.x;
  if (c >= 32) return;
  double inv = 1.0 / (double)N1_;
  double mm[4];
#pragma unroll
  for (int k = 0; k < 4; ++k) mm[k] = mom[k] * inv;
  double M[4][4];
  M[0][0] = mom[4] * inv;  M[0][1] = mom[5] * inv;  M[0][2] = mom[6] * inv;  M[0][3] = mom[7] * inv;
  M[1][1] = mom[8] * inv;  M[1][2] = mom[9] * inv;  M[1][3] = mom[10] * inv;
  M[2][2] = mom[11] * inv; M[2][3] = mom[12] * inv; M[3][3] = mom[13] * inv;
  M[1][0] = M[0][1]; M[2][0] = M[0][2]; M[3][0] = M[0][3];
  M[2][1] = M[1][2]; M[3][1] = M[1][3]; M[3][2] = M[2][3];
  double w[4];
#pragma unroll
  for (int k = 0; k < 4; ++k) w[k] = W0[k * 32 + c];
  double mean = 0.0;
#pragma unroll
  for (int k = 0; k < 4; ++k) mean += w[k] * mm[k];
  double e2 = 0.0;
#pragma unroll
  for (int k = 0; k < 4; ++k)
#pragma unroll
    for (int l = 0; l < 4; ++l) e2 += M[k][l] * w[k] * w[l];
  double var = e2 - mean * mean;
  double sc = (double)g0[c] / sqrt(var + EPS_);
  scale0[c] = (float)sc;
  shiftE0[c] = (float)((double)be0[c] - sc * mean);
}

// fused: project to 32ch + BN + LeakyReLU + Graclus pair-max pool -> x1 (N2,32)
__global__ __launch_bounds__(256) void k0_pool(const float* __restrict__ x,
    const float* __restrict__ T1, const float* __restrict__ T2, const float* __restrict__ T3,
    const float* __restrict__ W0, const float* __restrict__ scale0,
    const float* __restrict__ shiftE0, float* __restrict__ x1) {
  int gid = blockIdx.x * 256 + threadIdx.x;
  int grp = gid >> 5, c = gid & 31;
  if (grp >= N2_) return;
  int b = grp / E2_, j = grp - b * E2_;
  int ga = b * E1_ + 2 * j, gb = ga + 1;
  float w0 = W0[c], w1 = W0[32 + c], w2 = W0[64 + c], w3 = W0[96 + c];
  float da = x[ga] * w0 + T1[ga] * w1 + T2[ga] * w2 + T3[ga] * w3;
  float db = x[gb] * w0 + T1[gb] * w1 + T2[gb] * w2 + T3[gb] * w3;
  float sc = scale0[c], sh = shiftE0[c];
  float ya = lrelu(sc * da + sh), yb = lrelu(sc * db + sh);
  x1[grp * 32 + c] = fmaxf(ya, yb);
}

// =====================================================================
// Layer-1 Horner step with LDS-STAGED gather + fused self-projection:
//   O = x1 @ Q_j + L G    (do_gather=0 -> pure projection, pass for P3)
// Block = (graph, cgroup of 8 channels), 1024 threads. G/O in channel-
// group-major (CGM) layout: arr[cg][node][8] (slab = cg*N2*2 + g*E2*2
// float4s). Gather slab (4489 x 32 B = 143.6 KB) lives in LDS: gathers
// are served at LDS tier instead of L3 (R7: gather lines pinned at L3
// because kernel-boundary coherence evicts them from L2).
// In-place O == G is safe (G fully staged to LDS before any O store).
// do_stats: fused per-channel sum/sumsq of O into st[ch] / st[32+ch].
// =====================================================================
__global__ __launch_bounds__(1024) void k1_step(const float* __restrict__ X,
    const float* __restrict__ Gp, const int* __restrict__ src,
    const float* __restrict__ ew, const float* __restrict__ W1,
    float4 cf, float* __restrict__ O, int do_gather, int do_stats, double* st) {
  __shared__ float4 sG[E2_ * 2];      // 143.6 KB
  __shared__ float4 qs[32 * 2];       // [in][h] -> 4 output channels
  __shared__ float chAcc[2][2][4];    // [h][sum/sq][comp]
  int g = blockIdx.x >> 2, cg = blockIdx.x & 3;
  size_t slab = ((size_t)cg * N2_ + (size_t)g * E2_) * 2;   // float4 units
  int tid = threadIdx.x;
  if (tid < 64) {
    int in = tid >> 1, hh = tid & 1;
    const float* wp = W1 + in * 32 + cg * 8 + hh * 4;
    float4 q;
    q.x = cf.x * wp[0] + cf.y * wp[1024]     + cf.z * wp[2048]     + cf.w * wp[3072];
    q.y = cf.x * wp[1] + cf.y * wp[1024 + 1] + cf.z * wp[2048 + 1] + cf.w * wp[3072 + 1];
    q.z = cf.x * wp[2] + cf.y * wp[1024 + 2] + cf.z * wp[2048 + 2] + cf.w * wp[3072 + 2];
    q.w = cf.x * wp[3] + cf.y * wp[1024 + 3] + cf.z * wp[2048 + 3] + cf.w * wp[3072 + 3];
    qs[in * 2 + hh] = q;
  }
  if (do_stats && tid < 16) ((float*)chAcc)[tid] = 0.f;
  if (do_gather) {
    const float4* Gs = (const float4*)Gp + slab;
    for (int i = tid; i < E2_ * 2; i += 1024) sG[i] = Gs[i];
  }
  __syncthreads();
  int h = tid & 1, pr = tid >> 1;
  int gbase = g * E2_;
  float4* Os = (float4*)O + slab;
  float4 ssum = {0.f, 0.f, 0.f, 0.f}, ssq = {0.f, 0.f, 0.f, 0.f};
  for (int na = pr; na < E2_; na += 1024) {
    int nb = na + 512;
    bool hasb = nb < E2_;
    float4 xa[8], xb[8];
    {
      const float4* pa = (const float4*)(X + (size_t)(gbase + na) * 32);
#pragma unroll
      for (int t = 0; t < 8; ++t) xa[t] = pa[t];
    }
    if (hasb) {
      const float4* pb = (const float4*)(X + (size_t)(gbase + nb) * 32);
#pragma unroll
      for (int t = 0; t < 8; ++t) xb[t] = pb[t];
    } else {
#pragma unroll
      for (int t = 0; t < 8; ++t) xb[t] = {0.f, 0.f, 0.f, 0.f};
    }
    float4 aa = {0.f, 0.f, 0.f, 0.f}, ab = {0.f, 0.f, 0.f, 0.f};
#pragma unroll
    for (int t = 0; t < 8; ++t) {
#pragma unroll
      for (int k = 0; k < 4; ++k) {
        float4 q = qs[(t * 4 + k) * 2 + h];
        float va = ((const float*)&xa[t])[k];
        float vb = ((const float*)&xb[t])[k];
        aa.x += va * q.x; aa.y += va * q.y; aa.z += va * q.z; aa.w += va * q.w;
        ab.x += vb * q.x; ab.y += vb * q.y; ab.z += vb * q.z; ab.w += vb * q.w;
      }
    }
    if (do_gather) {
      {
        const int4* s4 = (const int4*)(src + (size_t)(gbase + na) * DEG_);
        const float4* w4 = (const float4*)(ew + (size_t)(gbase + na) * DEG_);
#pragma unroll
        for (int j = 0; j < 4; ++j) {
          int4 s = s4[j]; float4 w = w4[j];
          float4 g0 = sG[(s.x - gbase) * 2 + h];
          float4 g1 = sG[(s.y - gbase) * 2 + h];
          float4 g2 = sG[(s.z - gbase) * 2 + h];
          float4 g3 = sG[(s.w - gbase) * 2 + h];
          aa.x += w.x * g0.x + w.y * g1.x + w.z * g2.x + w.w * g3.x;
          aa.y += w.x * g0.y + w.y * g1.y + w.z * g2.y + w.w * g3.y;
          aa.z += w.x * g0.z + w.y * g1.z + w.z * g2.z + w.w * g3.z;
          aa.w += w.x * g0.w + w.y * g1.w + w.z * g2.w + w.w * g3.w;
        }
      }
      if (hasb) {
        const int4* s4 = (const int4*)(src + (size_t)(gbase + nb) * DEG_);
        const float4* w4 = (const float4*)(ew + (size_t)(gbase + nb) * DEG_);
#pragma unroll
        for (int j = 0; j < 4; ++j) {
          int4 s = s4[j]; float4 w = w4[j];
          float4 g0 = sG[(s.x - gbase) * 2 + h];
          float4 g1 = sG[(s.y - gbase) * 2 + h];
          float4 g2 = sG[(s.z - gbase) * 2 + h];
          float4 g3 = sG[(s.w - gbase) * 2 + h];
          ab.x += w.x * g0.x + w.y * g1.x + w.z * g2.x + w.w * g3.x;
          ab.y += w.x * g0.y + w.y * g1.y + w.z * g2.y + w.w * g3.y;
          ab.z += w.x * g0.z + w.y * g1.z + w.z * g2.z + w.w * g3.z;
          ab.w += w.x * g0.w + w.y * g1.w + w.z * g2.w + w.w * g3.w;
        }
      }
    }
    Os[(size_t)na * 2 + h] = aa;
    if (hasb) Os[(size_t)nb * 2 + h] = ab;
    if (do_stats) {
      ssum.x += aa.x + ab.x; ssum.y += aa.y + ab.y;
      ssum.z += aa.z + ab.z; ssum.w += aa.w + ab.w;
      ssq.x += aa.x * aa.x + ab.x * ab.x; ssq.y += aa.y * aa.y + ab.y * ab.y;
      ssq.z += aa.z * aa.z + ab.z * ab.z; ssq.w += aa.w * aa.w + ab.w * ab.w;
    }
  }
  if (do_stats) {
    atomicAdd(&chAcc[h][0][0], ssum.x); atomicAdd(&chAcc[h][0][1], ssum.y);
    atomicAdd(&chAcc[h][0][2], ssum.z); atomicAdd(&chAcc[h][0][3], ssum.w);
    atomicAdd(&chAcc[h][1][0], ssq.x);  atomicAdd(&chAcc[h][1][1], ssq.y);
    atomicAdd(&chAcc[h][1][2], ssq.z);  atomicAdd(&chAcc[h][1][3], ssq.w);
    __syncthreads();
    if (tid < 8) {
      int hh = tid >> 2, c = tid & 3;
      int ch = cg * 8 + hh * 4 + c;
      atomicAdd(&st[ch], (double)chAcc[hh][0][c]);
      atomicAdd(&st[32 + ch], (double)chAcc[hh][1][c]);
    }
  }
}

__global__ void k1_params(const double* __restrict__ sum, const double* __restrict__ sq,
    const float* __restrict__ g1, const float* __restrict__ be1,
    float* __restrict__ scale1, float* __restrict__ shiftE1) {
  int c = threadIdx.x;
  if (c >= 32) return;
  double mean = sum[c] / (double)N2_;
  double var = sq[c] / (double)N2_ - mean * mean;
  double sc = (double)g1[c] / sqrt(var + EPS_);
  scale1[c] = (float)sc;
  shiftE1[c] = (float)((double)be1[c] - sc * mean);
}

// =====================================================================
// Layer-2 Horner on 1-channel fields: u_j = f(out1) q_j (q_j from W2),
// out2 = u0 + L(u1 + L(u2 + L u3)).  b2 cancels in BN2.
// out1 is in CGM layout: float4 group t of node n at
// (t>>1)*(N2*2) + n*2 + (t&1); channel order ch = t*4+comp (unchanged).
// =====================================================================
__global__ __launch_bounds__(256) void k2_proj(const float* __restrict__ X,
    const float* __restrict__ W2, const float* __restrict__ scale1,
    const float* __restrict__ shiftE1,
    float* __restrict__ u0, float* __restrict__ u1,
    float* __restrict__ u2, float* __restrict__ u3) {
  __shared__ float qv[4][32];
  __shared__ float fsc[32], fsh[32];
  int tid = threadIdx.x;
  if (tid < 128) {
    int cp = tid & 31, j = tid >> 5;
    float w0 = W2[cp], w1 = W2[32 + cp], w2 = W2[64 + cp], w3 = W2[96 + cp];
    float q;
    if (j == 0)      q = w0 + w1 + w2 + w3;
    else if (j == 1) q = -w1 - 2.f * w2 - 3.f * w3;
    else if (j == 2) q = 0.5f * w2 + 1.5f * w3;
    else             q = -w3 * (1.f / 6.f);
    qv[j][cp] = q;
  }
  if (tid < 32) { fsc[tid] = scale1[tid]; fsh[tid] = shiftE1[tid]; }
  __syncthreads();
  int node = blockIdx.x * 256 + tid;
  if (node >= N2_) return;
  const float4* xf = (const float4*)X;
  float a0 = 0.f, a1 = 0.f, a2 = 0.f, a3 = 0.f;
#pragma unroll
  for (int t = 0; t < 8; ++t) {
    float4 v = xf[(size_t)(t >> 1) * ((size_t)N2_ * 2) + (size_t)node * 2 + (t & 1)];
    float f0 = lrelu(fsc[4 * t] * v.x + fsh[4 * t]);
    float f1 = lrelu(fsc[4 * t + 1] * v.y + fsh[4 * t + 1]);
    float f2_ = lrelu(fsc[4 * t + 2] * v.z + fsh[4 * t + 2]);
    float f3 = lrelu(fsc[4 * t + 3] * v.w + fsh[4 * t + 3]);
    a0 += f0 * qv[0][4 * t] + f1 * qv[0][4 * t + 1] + f2_ * qv[0][4 * t + 2] + f3 * qv[0][4 * t + 3];
    a1 += f0 * qv[1][4 * t] + f1 * qv[1][4 * t + 1] + f2_ * qv[1][4 * t + 2] + f3 * qv[1][4 * t + 3];
    a2 += f0 * qv[2][4 * t] + f1 * qv[2][4 * t + 1] + f2_ * qv[2][4 * t + 2] + f3 * qv[2][4 * t + 3];
    a3 += f0 * qv[3][4 * t] + f1 * qv[3][4 * t + 1] + f2_ * qv[3][4 * t + 2] + f3 * qv[3][4 * t + 3];
  }
  u0[node] = a0; u1[node] = a1; u2[node] = a2; u3[node] = a3;
}

// k2_step: zo = u + L z (1-channel), per-graph z slab in LDS.
__global__ __launch_bounds__(256) void k2_step(const float* __restrict__ z,
    const int* __restrict__ src, const float* __restrict__ ew,
    const float* __restrict__ u, float* __restrict__ zo,
    int do_stats, double* st2) {
  __shared__ float sz[E2_];
  __shared__ double sred[4][2];
  int g = blockIdx.x >> 2, q = blockIdx.x & 3;
  int gbase = g * E2_;
  for (int j = threadIdx.x; j < E2_; j += 256) sz[j] = z[gbase + j];
  __syncthreads();
  int start = q * QTR2_, end = min(start + QTR2_, E2_);
  double aS = 0.0, aQ = 0.0;
  for (int i = start + (int)threadIdx.x; i < end; i += 256) {
    int node = gbase + i;
    const int4* s4 = (const int4*)(src + (size_t)node * DEG_);
    const float4* w4 = (const float4*)(ew + (size_t)node * DEG_);
    float acc = 0.f;
#pragma unroll
    for (int j = 0; j < 4; ++j) {
      int4 s = s4[j]; float4 w = w4[j];
      acc += w.x * sz[s.x - gbase] + w.y * sz[s.y - gbase]
           + w.z * sz[s.z - gbase] + w.w * sz[s.w - gbase];
    }
    float val = u[node] + acc;
    zo[node] = val;
    if (do_stats) { aS += val; aQ += (double)val * (double)val; }
  }
  if (do_stats) {
    int lane = threadIdx.x & 63, wid = threadIdx.x >> 6;
    for (int o = 32; o; o >>= 1) { aS += __shfl_down(aS, o); aQ += __shfl_down(aQ, o); }
    if (lane == 0) { sred[wid][0] = aS; sred[wid][1] = aQ; }
    __syncthreads();
    if (threadIdx.x == 0) {
      double s = sred[0][0] + sred[1][0] + sred[2][0] + sred[3][0];
      double qq = sred[0][1] + sred[1][1] + sred[2][1] + sred[3][1];
      atomicAdd(&st2[0], s); atomicAdd(&st2[1], qq);
    }
  }
}

__global__ void k2_params(const double* __restrict__ st2, const float* __restrict__ g2,
    const float* __restrict__ be2, float* __restrict__ p /* [128]=scale2 [129]=shiftE2 */) {
  if (threadIdx.x != 0) return;
  double mean = st2[0] / (double)N2_;
  double var = st2[1] / (double)N2_ - mean * mean;
  double sc = (double)g2[0] / sqrt(var + EPS_);
  p[128] = (float)sc;
  p[129] = (float)((double)be2[0] - sc * mean);
}

// MLP gemm1: h1pre[b,c] = sum_r f2(out2[b*E2+r]) * lin1_W[r,c]
__global__ __launch_bounds__(256) void k3_gemm1(const float* __restrict__ out2,
    const float* __restrict__ lin1W, const float* __restrict__ p, float* h1pre) {
  __shared__ float f2v[4][284];
  float sc = p[128], sh = p[129];
  int bs = blockIdx.x & 15, rs = blockIdx.x >> 4;
  int b0 = bs * 4;
  int r0 = rs * 281;
  int nr = min(281, E2_ - r0);
  int c = threadIdx.x;
#pragma unroll
  for (int b = 0; b < 4; ++b)
    for (int j = c; j < 284; j += 256)
      f2v[b][j] = (j < nr) ? lrelu(sc * out2[(b0 + b) * E2_ + r0 + j] + sh) : 0.f;
  __syncthreads();
  float acc0 = 0.f, acc1 = 0.f, acc2 = 0.f, acc3 = 0.f;
  int nr4 = nr & ~3;
  int j = 0;
  for (; j < nr4; j += 4) {
    const float* wp = lin1W + (size_t)(r0 + j) * 256 + c;
    float w0 = wp[0], w1 = wp[256], w2 = wp[512], w3 = wp[768];
    float4 f0 = *(const float4*)&f2v[0][j];
    float4 f1 = *(const float4*)&f2v[1][j];
    float4 f2_ = *(const float4*)&f2v[2][j];
    float4 f3 = *(const float4*)&f2v[3][j];
    acc0 += f0.x * w0 + f0.y * w1 + f0.z * w2 + f0.w * w3;
    acc1 += f1.x * w0 + f1.y * w1 + f1.z * w2 + f1.w * w3;
    acc2 += f2_.x * w0 + f2_.y * w1 + f2_.z * w2 + f2_.w * w3;
    acc3 += f3.x * w0 + f3.y * w1 + f3.z * w2 + f3.w * w3;
  }
  for (; j < nr; ++j) {
    float w = lin1W[(size_t)(r0 + j) * 256 + c];
    acc0 += f2v[0][j] * w;
    acc1 += f2v[1][j] * w;
    acc2 += f2v[2][j] * w;
    acc3 += f2v[3][j] * w;
  }
  atomicAdd(&h1pre[(b0 + 0) * 256 + c], acc0);
  atomicAdd(&h1pre[(b0 + 1) * 256 + c], acc1);
  atomicAdd(&h1pre[(b0 + 2) * 256 + c], acc2);
  atomicAdd(&h1pre[(b0 + 3) * 256 + c], acc3);
}

// BN1 + ReLU -> h1 (64,256)
__global__ __launch_bounds__(256) void k4_bn1(const float* __restrict__ h1pre,
    const float* __restrict__ g, const float* __restrict__ be, float* __restrict__ h1) {
  int c = threadIdx.x;
  float vs[64];
  double s = 0.0, q = 0.0;
  for (int b = 0; b < 64; ++b) { float v = h1pre[b * 256 + c]; vs[b] = v; s += v; q += (double)v * v; }
  double mean = s / 64.0, var = q / 64.0 - mean * mean;
  double scd = (double)g[c] / sqrt(var + EPS_);
  double shd = (double)be[c] - scd * mean;
  for (int b = 0; b < 64; ++b) {
    float y = (float)(scd * vs[b] + shd);
    h1[b * 256 + c] = y > 0.f ? y : 0.f;
  }
}

// gemm2: 128 blocks, block = output column
__global__ __launch_bounds__(256) void k5_gemm2(const float* __restrict__ h1,
    const float* __restrict__ lin2W, float* __restrict__ h2pre) {
  __shared__ float sred[256];
  int c = blockIdx.x;
  int b = threadIdx.x & 63, q = threadIdx.x >> 6;
  float acc = 0.f;
  for (int r = q; r < 256; r += 4) acc += h1[b * 256 + r] * lin2W[r * 128 + c];
  sred[threadIdx.x] = acc;
  __syncthreads();
  if (threadIdx.x < 64)
    h2pre[threadIdx.x * 128 + c] = sred[threadIdx.x] + sred[64 + threadIdx.x]
                                 + sred[128 + threadIdx.x] + sred[192 + threadIdx.x];
}

// BN2 + ReLU + final linear -> out[64]
__global__ __launch_bounds__(256) void k6_final(const float* __restrict__ h2pre,
    const float* __restrict__ g, const float* __restrict__ be,
    const float* __restrict__ W3, const float* __restrict__ b3, float* __restrict__ outp) {
  __shared__ float sh2[64 * 129];
  __shared__ float sred[256];
  int tid = threadIdx.x;
  if (tid < 128) {
    int c = tid;
    float vs[64];
    double s = 0.0, q = 0.0;
    for (int b = 0; b < 64; ++b) { float v = h2pre[b * 128 + c]; vs[b] = v; s += v; q += (double)v * v; }
    double mean = s / 64.0, var = q / 64.0 - mean * mean;
    double scd = (double)g[c] / sqrt(var + EPS_);
    double shd = (double)be[c] - scd * mean;
    for (int b = 0; b < 64; ++b) {
      float y = (float)(scd * vs[b] + shd);
      sh2[b * 129 + c] = y > 0.f ? y : 0.f;
    }
  }
  __syncthreads();
  int b = tid & 63, q = tid >> 6;
  float acc = 0.f;
  for (int r = q; r < 128; r += 4) acc += sh2[b * 129 + r] * W3[r];
  sred[tid] = acc;
  __syncthreads();
  if (tid < 64)
    outp[tid] = sred[tid] + sred[64 + tid] + sred[128 + tid] + sred[192 + tid] + b3[0];
}

// =====================================================================
extern "C" void kernel_launch(void* const* d_in, const int* in_sizes, int n_in,
                              void* d_out, int out_size, void* d_ws, size_t ws_size,
                              hipStream_t stream) {
  const float* x    = (const float*)d_in[0];
  const int*   ei1  = (const int*)d_in[1];
  const float* ew1  = (const float*)d_in[2];
  const int*   ei2  = (const int*)d_in[3];
  const float* ew2  = (const float*)d_in[4];
  const float* W0   = (const float*)d_in[5];
  const float* g0   = (const float*)d_in[7];
  const float* be0  = (const float*)d_in[8];
  const float* W1   = (const float*)d_in[9];
  const float* g1   = (const float*)d_in[11];
  const float* be1  = (const float*)d_in[12];
  const float* W2   = (const float*)d_in[13];
  const float* g2   = (const float*)d_in[15];
  const float* be2  = (const float*)d_in[16];
  const float* lin1W = (const float*)d_in[17];
  const float* bn1g = (const float*)d_in[19];
  const float* bn1b = (const float*)d_in[20];
  const float* lin2W = (const float*)d_in[21];
  const float* bn2g = (const float*)d_in[23];
  const float* bn2b = (const float*)d_in[24];
  const float* lin3W = (const float*)d_in[25];
  const float* lin3b = (const float*)d_in[26];

  char* ws = (char*)d_ws;
  double* stats  = (double*)ws;                 // [0..13] mom0, [14..45] s1sum, [46..77] s1sq, [78..79] st2
  float*  params = (float*)(ws + 1024);         // scale0[32] shiftE0[32] scale1[32] shiftE1[32] ... [128..129]
  float*  h1pre  = (float*)(ws + 4096);
  float*  h1     = (float*)(ws + 4096 + 65536);
  float*  h2pre  = (float*)(ws + 4096 + 131072);
  // Treg: 3*N1 floats. Layer-0 T arrays live here; later overlaid by u/z/out2
  float*  Treg   = (float*)(ws + 262144);
  float* T1_0 = Treg;
  float* T2_0 = Treg + N1_;
  float* T3_0 = Treg + 2 * (size_t)N1_;
  float* u0   = Treg;                           // overlays (T dead after k0_pool)
  float* u1   = Treg + (size_t)N2_;
  float* u2   = Treg + 2 * (size_t)N2_;
  float* u3   = Treg + 3 * (size_t)N2_;
  float* zA   = Treg + 4 * (size_t)N2_;
  float* out2 = Treg + 5 * (size_t)N2_;         // 6*N2 <= 3*N1  ✓
  float*  big = (float*)(ws + 262144 + 3 * (size_t)N1_ * 4);
  float* bufA = big;                            // x1 (row-major, live through all of layer 1)
  float* bufB = bufA + 32 * (size_t)N2_;        // P3 -> Z2 -> Z1 -> out1 (CGM, in-place)

  hipMemsetAsync(stats, 0, 80 * sizeof(double), stream);
  hipMemsetAsync(h1pre, 0, 65536, stream);

  // ---- layer 0 ----
  k0_mv1<<<256, 256, 0, stream>>>(x, ei1, ew1, T1_0);
  k0_mv2<<<256, 256, 0, stream>>>(x, ei1, ew1, T1_0, T2_0);
  k0_mv3<<<256, 256, 0, stream>>>(x, ei1, ew1, T1_0, T2_0, T3_0, stats);
  k0_params<<<1, 32, 0, stream>>>(stats, W0, g0, be0, params, params + 32);
  k0_pool<<<MVGRID, 256, 0, stream>>>(x, T1_0, T2_0, T3_0, W0, params, params + 32, bufA);

  // ---- layer 1 (Horner, LDS-staged gathers, all in-place on bufB) ----
  float4 cQ3 = {0.f, 0.f, 0.f, -1.f / 6.f};
  float4 cQ2 = {0.f, 0.f, 0.5f, 1.5f};
  float4 cQ1 = {0.f, -1.f, -2.f, -3.f};
  float4 cQ0 = {1.f, 1.f, 1.f, 1.f};
  k1_step<<<256, 1024, 0, stream>>>(bufA, nullptr, ei2, ew2, W1, cQ3, bufB, 0, 0, nullptr); // P3
  k1_step<<<256, 1024, 0, stream>>>(bufA, bufB, ei2, ew2, W1, cQ2, bufB, 1, 0, nullptr);    // Z2
  k1_step<<<256, 1024, 0, stream>>>(bufA, bufB, ei2, ew2, W1, cQ1, bufB, 1, 0, nullptr);    // Z1
  k1_step<<<256, 1024, 0, stream>>>(bufA, bufB, ei2, ew2, W1, cQ0, bufB, 1, 1, stats + 14); // out1 + stats
  k1_params<<<1, 32, 0, stream>>>(stats + 14, stats + 46, g1, be1, params + 64, params + 96);

  // ---- layer 2 (Horner, 1-channel) ----
  k2_proj<<<(N2_ + 255) / 256, 256, 0, stream>>>(bufB, W2, params + 64, params + 96,
                                                 u0, u1, u2, u3);
  k2_step<<<256, 256, 0, stream>>>(u3, ei2, ew2, u2, zA, 0, nullptr);       // zA = u2 + L u3
  k2_step<<<256, 256, 0, stream>>>(zA, ei2, ew2, u1, u3, 0, nullptr);       // u3slot = u1 + L zA
  k2_step<<<256, 256, 0, stream>>>(u3, ei2, ew2, u0, out2, 1, stats + 78);  // out2 + stats
  k2_params<<<1, 64, 0, stream>>>(stats + 78, g2, be2, params);

  // ---- MLP head ----
  k3_gemm1<<<256, 256, 0, stream>>>(out2, lin1W, params, h1pre);
  k4_bn1<<<1, 256, 0, stream>>>(h1pre, bn1g, bn1b, h1);
  k5_gemm2<<<128, 256, 0, stream>>>(h1, lin2W, h2pre);
  k6_final<<<1, 256, 0, stream>>>(h2pre, bn2g, bn2b, lin3W, lin3b, (float*)d_out);
}

// Round 11
// 540.429 us; speedup vs baseline: 2.9795x; 2.9795x over previous
//
#include <hip/hip_runtime.h>
#include <cstdint>

#define SLOPE 0.33f

static constexpr int B_   = 64;
static constexpr int E1_  = 8978;
static constexpr int E2_  = 4489;
static constexpr int N1_  = B_ * E1_;      // 574592
static constexpr int N2_  = B_ * E2_;      // 287296
static constexpr int DEG_ = 16;
static constexpr int QTR_ = 2245;          // ceil(E1_/4)
static constexpr int QTR2_ = 1123;         // ceil(E2_/4)
static constexpr int MVGRID = (N2_ * 32) / 256;   // 35912 (exact)
static constexpr int PROJ_GRID = (N2_ + 511) / 512;  // 562
static constexpr double EPS_ = 1e-5;

__device__ __forceinline__ float lrelu(float v) { return v > 0.f ? v : SLOPE * v; }
__device__ __forceinline__ float dot4(float4 a, float4 b) {
  return a.x * b.x + a.y * b.y + a.z * b.z + a.w * b.w;
}

// =====================================================================
// Layer 0: 1 channel. Per-graph x slab staged in LDS; edges of node g are
// [g*16, g*16+16) by construction (dst sorted). grid = 64 graphs * 4 quarters.
// =====================================================================
__global__ __launch_bounds__(256) void k0_mv1(const float* __restrict__ x,
    const int* __restrict__ src, const float* __restrict__ ew, float* __restrict__ T1) {
  __shared__ float sx[E1_];
  int g = blockIdx.x >> 2, q = blockIdx.x & 3;
  int gbase = g * E1_;
  for (int j = threadIdx.x; j < E1_; j += 256) sx[j] = x[gbase + j];
  __syncthreads();
  int start = q * QTR_, end = min(start + QTR_, E1_);
  for (int i = start + (int)threadIdx.x; i < end; i += 256) {
    int node = gbase + i;
    const int4* s4 = (const int4*)(src + (size_t)node * DEG_);
    const float4* w4 = (const float4*)(ew + (size_t)node * DEG_);
    float acc = 0.f;
#pragma unroll
    for (int j = 0; j < 4; ++j) {
      int4 s = s4[j]; float4 w = w4[j];
      acc += w.x * sx[s.x - gbase] + w.y * sx[s.y - gbase]
           + w.z * sx[s.z - gbase] + w.w * sx[s.w - gbase];
    }
    T1[node] = sx[i] - acc;   // T1 = x - L x
  }
}

__global__ __launch_bounds__(256) void k0_mv2(const float* __restrict__ x,
    const int* __restrict__ src, const float* __restrict__ ew,
    const float* __restrict__ T1, float* __restrict__ T2) {
  __shared__ float sT[E1_];
  int g = blockIdx.x >> 2, q = blockIdx.x & 3;
  int gbase = g * E1_;
  for (int j = threadIdx.x; j < E1_; j += 256) sT[j] = T1[gbase + j];
  __syncthreads();
  int start = q * QTR_, end = min(start + QTR_, E1_);
  for (int i = start + (int)threadIdx.x; i < end; i += 256) {
    int node = gbase + i;
    const int4* s4 = (const int4*)(src + (size_t)node * DEG_);
    const float4* w4 = (const float4*)(ew + (size_t)node * DEG_);
    float acc = 0.f;
#pragma unroll
    for (int j = 0; j < 4; ++j) {
      int4 s = s4[j]; float4 w = w4[j];
      acc += w.x * sT[s.x - gbase] + w.y * sT[s.y - gbase]
           + w.z * sT[s.z - gbase] + w.w * sT[s.w - gbase];
    }
    T2[node] = (3.f * sT[i] - acc - x[node]) * 0.5f;  // T2 = (3T1 - L T1 - T0)/2
  }
}

// T3 = (5T2 - L T2 - 2T1)/3, plus moment accumulation for layer-0 BN.
__global__ __launch_bounds__(256) void k0_mv3(const float* __restrict__ x,
    const int* __restrict__ src, const float* __restrict__ ew,
    const float* __restrict__ T1, const float* __restrict__ T2,
    float* __restrict__ T3, double* mom) {
  __shared__ float sT[E1_];
  __shared__ double sred[4 * 14];
  int g = blockIdx.x >> 2, q = blockIdx.x & 3;
  int gbase = g * E1_;
  for (int j = threadIdx.x; j < E1_; j += 256) sT[j] = T2[gbase + j];
  __syncthreads();
  double m[14];
#pragma unroll
  for (int j = 0; j < 14; ++j) m[j] = 0.0;
  int start = q * QTR_, end = min(start + QTR_, E1_);
  for (int i = start + (int)threadIdx.x; i < end; i += 256) {
    int node = gbase + i;
    const int4* s4 = (const int4*)(src + (size_t)node * DEG_);
    const float4* w4 = (const float4*)(ew + (size_t)node * DEG_);
    float acc = 0.f;
#pragma unroll
    for (int j = 0; j < 4; ++j) {
      int4 s = s4[j]; float4 w = w4[j];
      acc += w.x * sT[s.x - gbase] + w.y * sT[s.y - gbase]
           + w.z * sT[s.z - gbase] + w.w * sT[s.w - gbase];
    }
    float t1 = T1[node];
    float t2 = sT[i];
    float t3 = (5.f * t2 - acc - 2.f * t1) * (1.f / 3.f);
    T3[node] = t3;
    double d0 = x[node], d1 = t1, d2 = t2, d3 = t3;
    m[0] += d0; m[1] += d1; m[2] += d2; m[3] += d3;
    m[4] += d0 * d0; m[5] += d0 * d1; m[6] += d0 * d2; m[7] += d0 * d3;
    m[8] += d1 * d1; m[9] += d1 * d2; m[10] += d1 * d3;
    m[11] += d2 * d2; m[12] += d2 * d3; m[13] += d3 * d3;
  }
  int lane = threadIdx.x & 63, wid = threadIdx.x >> 6;
#pragma unroll
  for (int j = 0; j < 14; ++j) {
    double v = m[j];
    for (int o = 32; o; o >>= 1) v += __shfl_down(v, o);
    if (lane == 0) sred[wid * 14 + j] = v;
  }
  __syncthreads();
  if (threadIdx.x < 14) {
    double s = sred[threadIdx.x] + sred[14 + threadIdx.x] + sred[28 + threadIdx.x] + sred[42 + threadIdx.x];
    atomicAdd(&mom[threadIdx.x], s);
  }
}

// BN params for layer 0 (b0 cancels in BN exactly).
__global__ void k0_params(const double* __restrict__ mom, const float* __restrict__ W0,
    const float* __restrict__ g0, const float* __restrict__ be0,
    float* __restrict__ scale0, float* __restrict__ shiftE0) {
  int c = threadIdx.x;
  if (c >= 32) return;
  double inv = 1.0 / (double)N1_;
  double mm[4];
#pragma unroll
  for (int k = 0; k < 4; ++k) mm[k] = mom[k] * inv;
  double M[4][4];
  M[0][0] = mom[4] * inv;  M[0][1] = mom[5] * inv;  M[0][2] = mom[6] * inv;  M[0][3] = mom[7] * inv;
  M[1][1] = mom[8] * inv;  M[1][2] = mom[9] * inv;  M[1][3] = mom[10] * inv;
  M[2][2] = mom[11] * inv; M[2][3] = mom[12] * inv; M[3][3] = mom[13] * inv;
  M[1][0] = M[0][1]; M[2][0] = M[0][2]; M[3][0] = M[0][3];
  M[2][1] = M[1][2]; M[3][1] = M[1][3]; M[3][2] = M[2][3];
  double w[4];
#pragma unroll
  for (int k = 0; k < 4; ++k) w[k] = W0[k * 32 + c];
  double mean = 0.0;
#pragma unroll
  for (int k = 0; k < 4; ++k) mean += w[k] * mm[k];
  double e2 = 0.0;
#pragma unroll
  for (int k = 0; k < 4; ++k)
#pragma unroll
    for (int l = 0; l < 4; ++l) e2 += M[k][l] * w[k] * w[l];
  double var = e2 - mean * mean;
  double sc = (double)g0[c] / sqrt(var + EPS_);
  scale0[c] = (float)sc;
  shiftE0[c] = (float)((double)be0[c] - sc * mean);
}

// fused: project to 32ch + BN + LeakyReLU + Graclus pair-max pool -> x1 (N2,32)
__global__ __launch_bounds__(256) void k0_pool(const float* __restrict__ x,
    const float* __restrict__ T1, const float* __restrict__ T2, const float* __restrict__ T3,
    const float* __restrict__ W0, const float* __restrict__ scale0,
    const float* __restrict__ shiftE0, float* __restrict__ x1) {
  int gid = blockIdx.x * 256 + threadIdx.x;
  int grp = gid >> 5, c = gid & 31;
  if (grp >= N2_) return;
  int b = grp / E2_, j = grp - b * E2_;
  int ga = b * E1_ + 2 * j, gb = ga + 1;
  float w0 = W0[c], w1 = W0[32 + c], w2 = W0[64 + c], w3 = W0[96 + c];
  float da = x[ga] * w0 + T1[ga] * w1 + T2[ga] * w2 + T3[ga] * w3;
  float db = x[gb] * w0 + T1[gb] * w1 + T2[gb] * w2 + T3[gb] * w3;
  float sc = scale0[c], sh = shiftE0[c];
  float ya = lrelu(sc * da + sh), yb = lrelu(sc * db + sh);
  x1[grp * 32 + c] = fmaxf(ya, yb);
}

// =====================================================================
// k1_projall: all four P_j = x1 @ Q_j in ONE pass (R5 structure, proven
// VGPR 124), but writes CGM PLANE layout: plane p = j*8+cg holds channels
// cg*4..cg*4+3 of P_(3-j')... plane blocks: [0,8)=P3 [8,16)=P2 [16,24)=P1
// [24,32)=P0.  P4[p*N2 + node] = float4. Per-wave per-plane stores are 64
// consecutive nodes x 16 B = 1 KB full lines (kills R5's 3x write inflation).
// =====================================================================
__global__ __launch_bounds__(256) void k1_projall(const float* __restrict__ X,
    const float* __restrict__ W1, float4* __restrict__ P4) {
  __shared__ float4 Wl[128 * 8];   // Wl[o*8+qq] = Q[4qq..4qq+3][o], o = j*32+c
  const float4 cfs[4] = { {0.f, 0.f, 0.f, -1.f / 6.f},    // Q3
                          {0.f, 0.f, 0.5f, 1.5f},          // Q2
                          {0.f, -1.f, -2.f, -3.f},         // Q1
                          {1.f, 1.f, 1.f, 1.f} };          // Q0
  for (int e = threadIdx.x; e < 1024; e += 256) {
    int o = e >> 3, qq = e & 7;
    int j = o >> 5, cp = o & 31;
    float4 cf = cfs[j];
    float4 w;
    {
      const float* wp = W1 + (4 * qq + 0) * 32 + cp;
      w.x = cf.x * wp[0] + cf.y * wp[1024] + cf.z * wp[2048] + cf.w * wp[3072];
    }
    {
      const float* wp = W1 + (4 * qq + 1) * 32 + cp;
      w.y = cf.x * wp[0] + cf.y * wp[1024] + cf.z * wp[2048] + cf.w * wp[3072];
    }
    {
      const float* wp = W1 + (4 * qq + 2) * 32 + cp;
      w.z = cf.x * wp[0] + cf.y * wp[1024] + cf.z * wp[2048] + cf.w * wp[3072];
    }
    {
      const float* wp = W1 + (4 * qq + 3) * 32 + cp;
      w.w = cf.x * wp[0] + cf.y * wp[1024] + cf.z * wp[2048] + cf.w * wp[3072];
    }
    Wl[e] = w;
  }
  __syncthreads();
  int rA = blockIdx.x * 512 + threadIdx.x;
  int rB = rA + 256;
  bool okA = rA < N2_, okB = rB < N2_;
  if (!okA) return;
  float4 xA[8], xB[8];
  {
    const float4* pa = (const float4*)(X + (size_t)rA * 32);
#pragma unroll
    for (int t = 0; t < 8; ++t) xA[t] = pa[t];
  }
  if (okB) {
    const float4* pb = (const float4*)(X + (size_t)rB * 32);
#pragma unroll
    for (int t = 0; t < 8; ++t) xB[t] = pb[t];
  } else {
#pragma unroll
    for (int t = 0; t < 8; ++t) xB[t] = {0.f, 0.f, 0.f, 0.f};
  }
  for (int oq = 0; oq < 32; ++oq) {
    float4 aA = {0.f, 0.f, 0.f, 0.f}, aB = {0.f, 0.f, 0.f, 0.f};
    const float4* wr = Wl + oq * 32;   // 4 outputs x 8 qq
#pragma unroll
    for (int qq = 0; qq < 8; ++qq) {
      float4 w0 = wr[0 * 8 + qq];
      float4 w1 = wr[1 * 8 + qq];
      float4 w2 = wr[2 * 8 + qq];
      float4 w3 = wr[3 * 8 + qq];
      float4 xa = xA[qq], xb = xB[qq];
      aA.x += dot4(xa, w0); aA.y += dot4(xa, w1); aA.z += dot4(xa, w2); aA.w += dot4(xa, w3);
      aB.x += dot4(xb, w0); aB.y += dot4(xb, w1); aB.z += dot4(xb, w2); aB.w += dot4(xb, w3);
    }
    P4[(size_t)oq * N2_ + rA] = aA;
    if (okB) P4[(size_t)oq * N2_ + rB] = aB;
  }
}

// =====================================================================
// k1_chain: full 3-step Horner chain for one (graph, 4-channel group).
// L is per-channel -> the chain closes over a cg slab. Two 71.8 KB LDS
// buffers ping-pong: stage P3 slab; step s: nxt = P_s(self, contiguous
// plane read) + L * cur (LDS gather); final out1 written over P3's plane
// (disjoint per (g,cg) -> safe). XCD swizzle co-locates a graph's 8 cg
// blocks so edge re-reads (3 steps x 8 cg) are served from one XCD's L2
// (4 graphs x 574 KB = 2.3 MB resident). BN stats fused into epilogue.
// =====================================================================
__global__ __launch_bounds__(1024) void k1_chain(const float4* __restrict__ P4,
    float4* __restrict__ O4, const int* __restrict__ src,
    const float* __restrict__ ew, double* st) {
  __shared__ float4 bA[E2_], bB[E2_];   // 2 x 71,824 B
  __shared__ float sacc[8];
  int v = (blockIdx.x & 7) * 64 + (blockIdx.x >> 3);   // XCD-contiguous graphs
  int g = v >> 3, cg = v & 7;
  int gbase = g * E2_;
  int tid = threadIdx.x;
  if (tid < 8) sacc[tid] = 0.f;
  {
    const float4* sp = P4 + (size_t)cg * N2_ + gbase;   // P3 plane slab
    for (int i = tid; i < E2_; i += 1024) bA[i] = sp[i];
  }
  float4* cur = bA;
  float4* nxt = bB;
  for (int s = 1; s <= 3; ++s) {
    __syncthreads();
    const float4* selfp = P4 + (size_t)(s * 8 + cg) * N2_ + gbase;
    for (int n = tid; n < E2_; n += 1024) {
      const int4* s4 = (const int4*)(src + (size_t)(gbase + n) * DEG_);
      const float4* w4 = (const float4*)(ew + (size_t)(gbase + n) * DEG_);
      float4 acc = selfp[n];
#pragma unroll
      for (int j = 0; j < 4; ++j) {
        int4 sx = s4[j]; float4 w = w4[j];
        float4 g0 = cur[sx.x - gbase];
        float4 g1 = cur[sx.y - gbase];
        float4 g2 = cur[sx.z - gbase];
        float4 g3 = cur[sx.w - gbase];
        acc.x += w.x * g0.x + w.y * g1.x + w.z * g2.x + w.w * g3.x;
        acc.y += w.x * g0.y + w.y * g1.y + w.z * g2.y + w.w * g3.y;
        acc.z += w.x * g0.z + w.y * g1.z + w.z * g2.z + w.w * g3.z;
        acc.w += w.x * g0.w + w.y * g1.w + w.z * g2.w + w.w * g3.w;
      }
      nxt[n] = acc;
    }
    float4* t = cur; cur = nxt; nxt = t;
  }
  __syncthreads();
  float4* op = O4 + (size_t)cg * N2_ + gbase;   // over P3 plane: disjoint per (g,cg)
  float4 s1 = {0.f, 0.f, 0.f, 0.f}, s2 = {0.f, 0.f, 0.f, 0.f};
  for (int n = tid; n < E2_; n += 1024) {
    float4 vv = cur[n];
    op[n] = vv;
    s1.x += vv.x; s1.y += vv.y; s1.z += vv.z; s1.w += vv.w;
    s2.x += vv.x * vv.x; s2.y += vv.y * vv.y; s2.z += vv.z * vv.z; s2.w += vv.w * vv.w;
  }
  for (int o = 32; o; o >>= 1) {
    s1.x += __shfl_down(s1.x, o); s1.y += __shfl_down(s1.y, o);
    s1.z += __shfl_down(s1.z, o); s1.w += __shfl_down(s1.w, o);
    s2.x += __shfl_down(s2.x, o); s2.y += __shfl_down(s2.y, o);
    s2.z += __shfl_down(s2.z, o); s2.w += __shfl_down(s2.w, o);
  }
  if ((tid & 63) == 0) {
    atomicAdd(&sacc[0], s1.x); atomicAdd(&sacc[1], s1.y);
    atomicAdd(&sacc[2], s1.z); atomicAdd(&sacc[3], s1.w);
    atomicAdd(&sacc[4], s2.x); atomicAdd(&sacc[5], s2.y);
    atomicAdd(&sacc[6], s2.z); atomicAdd(&sacc[7], s2.w);
  }
  __syncthreads();
  if (tid < 4) {
    int ch = cg * 4 + tid;
    atomicAdd(&st[ch], (double)sacc[tid]);
    atomicAdd(&st[32 + ch], (double)sacc[4 + tid]);
  }
}

__global__ void k1_params(const double* __restrict__ sum, const double* __restrict__ sq,
    const float* __restrict__ g1, const float* __restrict__ be1,
    float* __restrict__ scale1, float* __restrict__ shiftE1) {
  int c = threadIdx.x;
  if (c >= 32) return;
  double mean = sum[c] / (double)N2_;
  double var = sq[c] / (double)N2_ - mean * mean;
  double sc = (double)g1[c] / sqrt(var + EPS_);
  scale1[c] = (float)sc;
  shiftE1[c] = (float)((double)be1[c] - sc * mean);
}

// =====================================================================
// Layer-2 Horner on 1-channel fields: u_j = f(out1) q_j (q_j from W2),
// out2 = u0 + L(u1 + L(u2 + L u3)).  b2 cancels in BN2.
// out1 is in PLANE layout: plane t (t=0..7) holds channels 4t..4t+3;
// float4 of node at xf[t*N2 + node].
// =====================================================================
__global__ __launch_bounds__(256) void k2_proj(const float* __restrict__ X,
    const float* __restrict__ W2, const float* __restrict__ scale1,
    const float* __restrict__ shiftE1,
    float* __restrict__ u0, float* __restrict__ u1,
    float* __restrict__ u2, float* __restrict__ u3) {
  __shared__ float qv[4][32];
  __shared__ float fsc[32], fsh[32];
  int tid = threadIdx.x;
  if (tid < 128) {
    int cp = tid & 31, j = tid >> 5;
    float w0 = W2[cp], w1 = W2[32 + cp], w2 = W2[64 + cp], w3 = W2[96 + cp];
    float q;
    if (j == 0)      q = w0 + w1 + w2 + w3;
    else if (j == 1) q = -w1 - 2.f * w2 - 3.f * w3;
    else if (j == 2) q = 0.5f * w2 + 1.5f * w3;
    else             q = -w3 * (1.f / 6.f);
    qv[j][cp] = q;
  }
  if (tid < 32) { fsc[tid] = scale1[tid]; fsh[tid] = shiftE1[tid]; }
  __syncthreads();
  int node = blockIdx.x * 256 + tid;
  if (node >= N2_) return;
  const float4* xf = (const float4*)X;
  float a0 = 0.f, a1 = 0.f, a2 = 0.f, a3 = 0.f;
#pragma unroll
  for (int t = 0; t < 8; ++t) {
    float4 v = xf[(size_t)t * N2_ + node];
    float f0 = lrelu(fsc[4 * t] * v.x + fsh[4 * t]);
    float f1 = lrelu(fsc[4 * t + 1] * v.y + fsh[4 * t + 1]);
    float f2_ = lrelu(fsc[4 * t + 2] * v.z + fsh[4 * t + 2]);
    float f3 = lrelu(fsc[4 * t + 3] * v.w + fsh[4 * t + 3]);
    a0 += f0 * qv[0][4 * t] + f1 * qv[0][4 * t + 1] + f2_ * qv[0][4 * t + 2] + f3 * qv[0][4 * t + 3];
    a1 += f0 * qv[1][4 * t] + f1 * qv[1][4 * t + 1] + f2_ * qv[1][4 * t + 2] + f3 * qv[1][4 * t + 3];
    a2 += f0 * qv[2][4 * t] + f1 * qv[2][4 * t + 1] + f2_ * qv[2][4 * t + 2] + f3 * qv[2][4 * t + 3];
    a3 += f0 * qv[3][4 * t] + f1 * qv[3][4 * t + 1] + f2_ * qv[3][4 * t + 2] + f3 * qv[3][4 * t + 3];
  }
  u0[node] = a0; u1[node] = a1; u2[node] = a2; u3[node] = a3;
}

// k2_step: zo = u + L z (1-channel), per-graph z slab in LDS.
__global__ __launch_bounds__(256) void k2_step(const float* __restrict__ z,
    const int* __restrict__ src, const float* __restrict__ ew,
    const float* __restrict__ u, float* __restrict__ zo,
    int do_stats, double* st2) {
  __shared__ float sz[E2_];
  __shared__ double sred[4][2];
  int g = blockIdx.x >> 2, q = blockIdx.x & 3;
  int gbase = g * E2_;
  for (int j = threadIdx.x; j < E2_; j += 256) sz[j] = z[gbase + j];
  __syncthreads();
  int start = q * QTR2_, end = min(start + QTR2_, E2_);
  double aS = 0.0, aQ = 0.0;
  for (int i = start + (int)threadIdx.x; i < end; i += 256) {
    int node = gbase + i;
    const int4* s4 = (const int4*)(src + (size_t)node * DEG_);
    const float4* w4 = (const float4*)(ew + (size_t)node * DEG_);
    float acc = 0.f;
#pragma unroll
    for (int j = 0; j < 4; ++j) {
      int4 s = s4[j]; float4 w = w4[j];
      acc += w.x * sz[s.x - gbase] + w.y * sz[s.y - gbase]
           + w.z * sz[s.z - gbase] + w.w * sz[s.w - gbase];
    }
    float val = u[node] + acc;
    zo[node] = val;
    if (do_stats) { aS += val; aQ += (double)val * (double)val; }
  }
  if (do_stats) {
    int lane = threadIdx.x & 63, wid = threadIdx.x >> 6;
    for (int o = 32; o; o >>= 1) { aS += __shfl_down(aS, o); aQ += __shfl_down(aQ, o); }
    if (lane == 0) { sred[wid][0] = aS; sred[wid][1] = aQ; }
    __syncthreads();
    if (threadIdx.x == 0) {
      double s = sred[0][0] + sred[1][0] + sred[2][0] + sred[3][0];
      double qq = sred[0][1] + sred[1][1] + sred[2][1] + sred[3][1];
      atomicAdd(&st2[0], s); atomicAdd(&st2[1], qq);
    }
  }
}

__global__ void k2_params(const double* __restrict__ st2, const float* __restrict__ g2,
    const float* __restrict__ be2, float* __restrict__ p /* [128]=scale2 [129]=shiftE2 */) {
  if (threadIdx.x != 0) return;
  double mean = st2[0] / (double)N2_;
  double var = st2[1] / (double)N2_ - mean * mean;
  double sc = (double)g2[0] / sqrt(var + EPS_);
  p[128] = (float)sc;
  p[129] = (float)((double)be2[0] - sc * mean);
}

// MLP gemm1: h1pre[b,c] = sum_r f2(out2[b*E2+r]) * lin1_W[r,c]
__global__ __launch_bounds__(256) void k3_gemm1(const float* __restrict__ out2,
    const float* __restrict__ lin1W, const float* __restrict__ p, float* h1pre) {
  __shared__ float f2v[4][284];
  float sc = p[128], sh = p[129];
  int bs = blockIdx.x & 15, rs = blockIdx.x >> 4;
  int b0 = bs * 4;
  int r0 = rs * 281;
  int nr = min(281, E2_ - r0);
  int c = threadIdx.x;
#pragma unroll
  for (int b = 0; b < 4; ++b)
    for (int j = c; j < 284; j += 256)
      f2v[b][j] = (j < nr) ? lrelu(sc * out2[(b0 + b) * E2_ + r0 + j] + sh) : 0.f;
  __syncthreads();
  float acc0 = 0.f, acc1 = 0.f, acc2 = 0.f, acc3 = 0.f;
  int nr4 = nr & ~3;
  int j = 0;
  for (; j < nr4; j += 4) {
    const float* wp = lin1W + (size_t)(r0 + j) * 256 + c;
    float w0 = wp[0], w1 = wp[256], w2 = wp[512], w3 = wp[768];
    float4 f0 = *(const float4*)&f2v[0][j];
    float4 f1 = *(const float4*)&f2v[1][j];
    float4 f2_ = *(const float4*)&f2v[2][j];
    float4 f3 = *(const float4*)&f2v[3][j];
    acc0 += f0.x * w0 + f0.y * w1 + f0.z * w2 + f0.w * w3;
    acc1 += f1.x * w0 + f1.y * w1 + f1.z * w2 + f1.w * w3;
    acc2 += f2_.x * w0 + f2_.y * w1 + f2_.z * w2 + f2_.w * w3;
    acc3 += f3.x * w0 + f3.y * w1 + f3.z * w2 + f3.w * w3;
  }
  for (; j < nr; ++j) {
    float w = lin1W[(size_t)(r0 + j) * 256 + c];
    acc0 += f2v[0][j] * w;
    acc1 += f2v[1][j] * w;
    acc2 += f2v[2][j] * w;
    acc3 += f2v[3][j] * w;
  }
  atomicAdd(&h1pre[(b0 + 0) * 256 + c], acc0);
  atomicAdd(&h1pre[(b0 + 1) * 256 + c], acc1);
  atomicAdd(&h1pre[(b0 + 2) * 256 + c], acc2);
  atomicAdd(&h1pre[(b0 + 3) * 256 + c], acc3);
}

// BN1 + ReLU -> h1 (64,256)
__global__ __launch_bounds__(256) void k4_bn1(const float* __restrict__ h1pre,
    const float* __restrict__ g, const float* __restrict__ be, float* __restrict__ h1) {
  int c = threadIdx.x;
  float vs[64];
  double s = 0.0, q = 0.0;
  for (int b = 0; b < 64; ++b) { float v = h1pre[b * 256 + c]; vs[b] = v; s += v; q += (double)v * v; }
  double mean = s / 64.0, var = q / 64.0 - mean * mean;
  double scd = (double)g[c] / sqrt(var + EPS_);
  double shd = (double)be[c] - scd * mean;
  for (int b = 0; b < 64; ++b) {
    float y = (float)(scd * vs[b] + shd);
    h1[b * 256 + c] = y > 0.f ? y : 0.f;
  }
}

// gemm2: 128 blocks, block = output column
__global__ __launch_bounds__(256) void k5_gemm2(const float* __restrict__ h1,
    const float* __restrict__ lin2W, float* __restrict__ h2pre) {
  __shared__ float sred[256];
  int c = blockIdx.x;
  int b = threadIdx.x & 63, q = threadIdx.x >> 6;
  float acc = 0.f;
  for (int r = q; r < 256; r += 4) acc += h1[b * 256 + r] * lin2W[r * 128 + c];
  sred[threadIdx.x] = acc;
  __syncthreads();
  if (threadIdx.x < 64)
    h2pre[threadIdx.x * 128 + c] = sred[threadIdx.x] + sred[64 + threadIdx.x]
                                 + sred[128 + threadIdx.x] + sred[192 + threadIdx.x];
}

// BN2 + ReLU + final linear -> out[64]
__global__ __launch_bounds__(256) void k6_final(const float* __restrict__ h2pre,
    const float* __restrict__ g, const float* __restrict__ be,
    const float* __restrict__ W3, const float* __restrict__ b3, float* __restrict__ outp) {
  __shared__ float sh2[64 * 129];
  __shared__ float sred[256];
  int tid = threadIdx.x;
  if (tid < 128) {
    int c = tid;
    float vs[64];
    double s = 0.0, q = 0.0;
    for (int b = 0; b < 64; ++b) { float v = h2pre[b * 128 + c]; vs[b] = v; s += v; q += (double)v * v; }
    double mean = s / 64.0, var = q / 64.0 - mean * mean;
    double scd = (double)g[c] / sqrt(var + EPS_);
    double shd = (double)be[c] - scd * mean;
    for (int b = 0; b < 64; ++b) {
      float y = (float)(scd * vs[b] + shd);
      sh2[b * 129 + c] = y > 0.f ? y : 0.f;
    }
  }
  __syncthreads();
  int b = tid & 63, q = tid >> 6;
  float acc = 0.f;
  for (int r = q; r < 128; r += 4) acc += sh2[b * 129 + r] * W3[r];
  sred[tid] = acc;
  __syncthreads();
  if (tid < 64)
    outp[tid] = sred[tid] + sred[64 + tid] + sred[128 + tid] + sred[192 + tid] + b3[0];
}

// =====================================================================
extern "C" void kernel_launch(void* const* d_in, const int* in_sizes, int n_in,
                              void* d_out, int out_size, void* d_ws, size_t ws_size,
                              hipStream_t stream) {
  const float* x    = (const float*)d_in[0];
  const int*   ei1  = (const int*)d_in[1];
  const float* ew1  = (const float*)d_in[2];
  const int*   ei2  = (const int*)d_in[3];
  const float* ew2  = (const float*)d_in[4];
  const float* W0   = (const float*)d_in[5];
  const float* g0   = (const float*)d_in[7];
  const float* be0  = (const float*)d_in[8];
  const float* W1   = (const float*)d_in[9];
  const float* g1   = (const float*)d_in[11];
  const float* be1  = (const float*)d_in[12];
  const float* W2   = (const float*)d_in[13];
  const float* g2   = (const float*)d_in[15];
  const float* be2  = (const float*)d_in[16];
  const float* lin1W = (const float*)d_in[17];
  const float* bn1g = (const float*)d_in[19];
  const float* bn1b = (const float*)d_in[20];
  const float* lin2W = (const float*)d_in[21];
  const float* bn2g = (const float*)d_in[23];
  const float* bn2b = (const float*)d_in[24];
  const float* lin3W = (const float*)d_in[25];
  const float* lin3b = (const float*)d_in[26];

  char* ws = (char*)d_ws;
  double* stats  = (double*)ws;                 // [0..13] mom0, [14..45] s1sum, [46..77] s1sq, [78..79] st2
  float*  params = (float*)(ws + 1024);         // scale0[32] shiftE0[32] scale1[32] shiftE1[32] ... [128..129]
  float*  h1pre  = (float*)(ws + 4096);
  float*  h1     = (float*)(ws + 4096 + 65536);
  float*  h2pre  = (float*)(ws + 4096 + 131072);
  // Treg: 3*N1 floats. Layer-0 T arrays live here; later overlaid by u/z/out2
  float*  Treg   = (float*)(ws + 262144);
  float* T1_0 = Treg;
  float* T2_0 = Treg + N1_;
  float* T3_0 = Treg + 2 * (size_t)N1_;
  float* u0   = Treg;                           // overlays (T dead after k0_pool)
  float* u1   = Treg + (size_t)N2_;
  float* u2   = Treg + 2 * (size_t)N2_;
  float* u3   = Treg + 3 * (size_t)N2_;
  float* zA   = Treg + 4 * (size_t)N2_;
  float* out2 = Treg + 5 * (size_t)N2_;         // 6*N2 <= 3*N1  ✓
  float*  big = (float*)(ws + 262144 + 3 * (size_t)N1_ * 4);
  float* bufA = big;                            // x1 row-major (32*N2)
  float* Pbuf = big + 32 * (size_t)N2_;         // 32 planes x N2 float4 (128*N2 floats)
                                                // planes [0,8)=P3 -> out1; [8,16)=P2; [16,24)=P1; [24,32)=P0

  hipMemsetAsync(stats, 0, 80 * sizeof(double), stream);
  hipMemsetAsync(h1pre, 0, 65536, stream);

  // ---- layer 0 ----
  k0_mv1<<<256, 256, 0, stream>>>(x, ei1, ew1, T1_0);
  k0_mv2<<<256, 256, 0, stream>>>(x, ei1, ew1, T1_0, T2_0);
  k0_mv3<<<256, 256, 0, stream>>>(x, ei1, ew1, T1_0, T2_0, T3_0, stats);
  k0_params<<<1, 32, 0, stream>>>(stats, W0, g0, be0, params, params + 32);
  k0_pool<<<MVGRID, 256, 0, stream>>>(x, T1_0, T2_0, T3_0, W0, params, params + 32, bufA);

  // ---- layer 1 (all four P_j in one pass, then LDS-resident Horner chain) ----
  k1_projall<<<PROJ_GRID, 256, 0, stream>>>(bufA, W1, (float4*)Pbuf);
  k1_chain<<<512, 1024, 0, stream>>>((const float4*)Pbuf, (float4*)Pbuf, ei2, ew2, stats + 14);
  k1_params<<<1, 32, 0, stream>>>(stats + 14, stats + 46, g1, be1, params + 64, params + 96);

  // ---- layer 2 (Horner, 1-channel; out1 = planes 0..7 of Pbuf) ----
  k2_proj<<<(N2_ + 255) / 256, 256, 0, stream>>>(Pbuf, W2, params + 64, params + 96,
                                                 u0, u1, u2, u3);
  k2_step<<<256, 256, 0, stream>>>(u3, ei2, ew2, u2, zA, 0, nullptr);       // zA = u2 + L u3
  k2_step<<<256, 256, 0, stream>>>(zA, ei2, ew2, u1, u3, 0, nullptr);       // u3slot = u1 + L zA
  k2_step<<<256, 256, 0, stream>>>(u3, ei2, ew2, u0, out2, 1, stats + 78);  // out2 + stats
  k2_params<<<1, 64, 0, stream>>>(stats + 78, g2, be2, params);

  // ---- MLP head ----
  k3_gemm1<<<256, 256, 0, stream>>>(out2, lin1W, params, h1pre);
  k4_bn1<<<1, 256, 0, stream>>>(h1pre, bn1g, bn1b, h1);
  k5_gemm2<<<128, 256, 0, stream>>>(h1, lin2W, h2pre);
  k6_final<<<1, 256, 0, stream>>>(h2pre, bn2g, bn2b, lin3W, lin3b, (float*)d_out);
}